// Round 6
// baseline (1102.996 us; speedup 1.0000x reference)
//
#include <hip/hip_runtime.h>

typedef __attribute__((ext_vector_type(8))) __bf16 bf16x8;
typedef __attribute__((ext_vector_type(4))) float f32x4;
typedef unsigned short u16;

#define B_    4
#define L_    4096
#define K_    12
#define ZC_   780        /* MEM + K */
#define CH2_  128        /* scan chunks */
#define CL2_  32         /* rows per chunk = L_/CH2_ */
#define PSTR_ 1752       /* packed projection row: 780 Z | 768 Q | 12 G | 192 LAT */
#define QOFF_ 780
#define GOFF_ 1548
#define LOFF_ 1560
#define WPAD_ 1920       /* WallT col padding: 10 tiles x 192 */

__device__ __forceinline__ float softplusf(float x){ return log1pf(__expf(x)); }
__device__ __forceinline__ float sigmoidf(float x){ return 1.f / (1.f + __expf(-x)); }
// f32 -> bf16 RNE (no NaN/Inf expected in this model)
__device__ __forceinline__ u16 f2bf(float x){
    unsigned u = __float_as_uint(x);
    u += 0x7FFFu + ((u >> 16) & 1u);
    return (u16)(u >> 16);
}
__device__ __forceinline__ float bf2f(u16 h){
    return __uint_as_float((unsigned)h << 16);
}

// async global->LDS, 16B per lane; LDS dest is linear (base + lane*16)
#define GLOAD16(gp, lp) __builtin_amdgcn_global_load_lds( \
    (const __attribute__((address_space(1))) unsigned int*)(gp), \
    (__attribute__((address_space(3))) unsigned int*)(lp), 16, 0, 0)

// bijective XCD swizzle (8 XCDs): contiguous wg chunk per XCD
__device__ __forceinline__ int xcd_swz(int bid, int nwg)
{
    const int q = nwg >> 3, r = nwg & 7;
    const int x = bid & 7, y = bid >> 3;
    return (x < r ? x * (q + 1) : r * (q + 1) + (x - r) * q) + y;
}

// dtype probe: score_scale == ones; f32 1.0 -> 0x3F800000
__global__ void probe_k(const unsigned* __restrict__ ss, int* __restrict__ md)
{
    if (threadIdx.x == 0 && blockIdx.x == 0) {
        unsigned w = ss[0];
        int m = 0;
        if      (w == 0x3F803F80u) m = 1;
        else if (w == 0x3C003C00u) m = 2;
        else if (w == 0x00000000u) m = 3;
        else if (w != 0x3F800000u) m = 4;
        md[0] = m;
    }
}

__global__ void fillf_k(float* __restrict__ p, long n, float v)
{
    for (long i = (long)blockIdx.x * blockDim.x + threadIdx.x; i < n;
         i += (long)gridDim.x * blockDim.x) p[i] = v;
}
__global__ void guard_k(const int* __restrict__ md, float* __restrict__ p, long n)
{
    const int m = *md;
    if (m == 0) return;
    for (long i = (long)blockIdx.x * blockDim.x + threadIdx.x; i < n;
         i += (long)gridDim.x * blockDim.x) p[i] = 4000.f + m;
}

// ---------------------------------------------------------------------------
// 8-phase split-bf16 MFMA GEMM (m201-style schedule, plain HIP). Single
// instantiation NF=3 (BN=192). C[M,N] = A[M,K] @ B[K,N] in ~f32 precision via
// the K'=3K extension: A' = [A_hi | A_hi | A_lo], B' = [B_hi ; B_lo ; B_hi]
// (pure per-tile base offsets into the packed layouts).
// A packed per row: [hi(0..K-1) | lo(0..K-1)] u16, row stride lda.
// B packed transposed per col n: [hi | lo], row stride ldb.
// Tile: BM=256, BN=192, BK=64, 512 thr = 8 waves (2M x 4N), 128x48 per wave.
// LDS 112 KiB double-buffered. Per phase: {ds_read quadrant frags, issue 1-2
// gload_lds, barrier, lgkm0+sched_barrier, setprio(1) 12 MFMA setprio(0),
// barrier}; counted vmcnt(3) only at phases 4/8. Staging: linear DMA dest +
// inverse-XOR-swizzled global source; reads XOR-deswizzle (chunk ^= row&7) ->
// bank-conflict-free (r4-verified: SQ_LDS_BANK_CONFLICT = 0).
// M mult of 256; Kseg mult of 64; nk = 3*Kseg/64 even.
// ---------------------------------------------------------------------------
template<int NF>
__global__ __launch_bounds__(512, 2) void gemm8_k(
    const u16* __restrict__ Ag, const u16* __restrict__ Bg,
    float* __restrict__ C, int N, int Kseg, int lda, int ldb, int ldc, int nTn)
{
    constexpr int BN = NF * 64;
    __shared__ __align__(16) u16 As[2][256][64];
    __shared__ __align__(16) u16 Bs[2][BN][64];

    const int wg = xcd_swz(blockIdx.x, gridDim.x);
    const int n0 = (wg % nTn) * BN, m0 = (wg / nTn) * 256;
    const int tid  = threadIdx.x;
    const int lane = tid & 63;
    const int wave = tid >> 6;
    const int wm = (wave >> 2) * 128, wn = (wave & 3) * (NF * 16);
    const int lr = lane & 15, lg = lane >> 4;
    const int t8 = tid >> 3, t7 = tid & 7;
    const int nk = (3 * Kseg) >> 6;

    f32x4 acc[8][NF];
    #pragma unroll
    for (int i = 0; i < 8; i++)
        #pragma unroll
        for (int j = 0; j < NF; j++) acc[i][j] = (f32x4){0.f, 0.f, 0.f, 0.f};
    bf16x8 bf[NF][2];

    auto AOFF = [&](int t) -> long {
        const int k0 = t * 64, s = k0 / Kseg, km = k0 - s * Kseg;
        return (long)((s < 2 ? 0 : Kseg) + km);
    };
    auto BOFF = [&](int t) -> long {
        const int k0 = t * 64, s = k0 / Kseg, km = k0 - s * Kseg;
        return (long)((s == 1 ? Kseg : 0) + km);
    };

#define FENCE() asm volatile("" ::: "memory")
#define BARR()  { FENCE(); __builtin_amdgcn_s_barrier(); FENCE(); }
#define LGKM0() { asm volatile("s_waitcnt lgkmcnt(0)" ::: "memory"); \
                  __builtin_amdgcn_sched_barrier(0); }
#define VMWB()  { asm volatile("s_waitcnt vmcnt(3)" ::: "memory"); }
#define STGA(BUF, OFF, R) { const int rl_ = (R)*64 + t8; \
    const int q_ = t7 ^ (rl_ & 7); \
    GLOAD16(Ag + (long)(m0 + rl_) * lda + (OFF) + q_*8, &As[BUF][rl_][t7*8]); }
#define STGB(BUF, OFF, R) { const int rl_ = (R)*64 + t8; \
    const int q_ = t7 ^ (rl_ & 7); \
    GLOAD16(Bg + (long)(n0 + rl_) * ldb + (OFF) + q_*8, &Bs[BUF][rl_][t7*8]); }
#define LOADB(BUF) { \
    _Pragma("unroll") for (int j = 0; j < NF; j++) { \
        _Pragma("unroll") for (int kk = 0; kk < 2; kk++) { \
            const int rb = wn + j*16 + lr; \
            const int c = (kk*4 + lg) ^ (rb & 7); \
            bf[j][kk] = *(const bf16x8*)&Bs[BUF][rb][c*8]; } } }
#define PHASE(BUF, Q, STG, WAITC) { \
    bf16x8 af[2][2]; \
    _Pragma("unroll") for (int e = 0; e < 2; e++) { \
        _Pragma("unroll") for (int kk = 0; kk < 2; kk++) { \
            const int ra = wm + (2*(Q)+e)*16 + lr; \
            const int c = (kk*4 + lg) ^ (ra & 7); \
            af[e][kk] = *(const bf16x8*)&As[BUF][ra][c*8]; } } \
    STG; WAITC; \
    BARR(); \
    LGKM0(); \
    __builtin_amdgcn_s_setprio(1); \
    _Pragma("unroll") for (int e = 0; e < 2; e++) { \
        _Pragma("unroll") for (int j = 0; j < NF; j++) { \
            acc[2*(Q)+e][j] = __builtin_amdgcn_mfma_f32_16x16x32_bf16( \
                af[e][0], bf[j][0], acc[2*(Q)+e][j], 0, 0, 0); \
            acc[2*(Q)+e][j] = __builtin_amdgcn_mfma_f32_16x16x32_bf16( \
                af[e][1], bf[j][1], acc[2*(Q)+e][j], 0, 0, 0); } } \
    __builtin_amdgcn_s_setprio(0); \
    __builtin_amdgcn_sched_barrier(0); \
    BARR(); }

    // prologue: stage A(0), B(0), B(1); wait A0+B0 (keep B1 in flight)
    {
        const long a0 = AOFF(0), b0 = BOFF(0), b1 = BOFF(1);
        STGA(0, a0, 0) STGA(0, a0, 1) STGA(0, a0, 2) STGA(0, a0, 3)
        STGB(0, b0, 0) STGB(0, b0, 1) STGB(0, b0, 2)
        STGB(1, b1, 0) STGB(1, b1, 1) STGB(1, b1, 2)
        VMWB();
        BARR();
    }

    const int nit = nk >> 1;
    for (int I = 0; I < nit; I++) {
        const int t1 = 2*I + 1;
        const int t2 = (2*I + 2 < nk) ? 2*I + 2 : nk - 1;
        const int t3 = (2*I + 3 < nk) ? 2*I + 3 : nk - 1;
        const long a1 = AOFF(t1), b2 = BOFF(t2), a2 = AOFF(t2), b3 = BOFF(t3);

        LOADB(0)
        PHASE(0, 0, { STGA(1, a1, 0) STGA(1, a1, 1) }, )
        PHASE(0, 1, { STGA(1, a1, 2) STGA(1, a1, 3) }, )
        PHASE(0, 2, { STGB(0, b2, 0) STGB(0, b2, 1) }, )
        PHASE(0, 3, { STGB(0, b2, 2) }, VMWB())
        LOADB(1)
        PHASE(1, 0, { STGA(0, a2, 0) STGA(0, a2, 1) }, )
        PHASE(1, 1, { STGA(0, a2, 2) STGA(0, a2, 3) }, )
        PHASE(1, 2, { STGB(1, b3, 0) STGB(1, b3, 1) }, )
        PHASE(1, 3, { STGB(1, b3, 2) }, VMWB())
    }
    asm volatile("s_waitcnt vmcnt(0)" ::: "memory");

    // D layout: col = lane&15, row = (lane>>4)*4 + reg
    #pragma unroll
    for (int i = 0; i < 8; i++) {
        #pragma unroll
        for (int j = 0; j < NF; j++) {
            const int gn = n0 + wn + j * 16 + lr;
            if (gn < N) {
                #pragma unroll
                for (int r = 0; r < 4; r++) {
                    const int gm = m0 + wm + i * 16 + lg * 4 + r;
                    C[(long)gm * ldc + gn] = acc[i][j][r];
                }
            }
        }
    }
#undef FENCE
#undef BARR
#undef LGKM0
#undef VMWB
#undef STGA
#undef STGB
#undef LOADB
#undef PHASE
}

// ---------------------------------------------------------------------------
// Fused stage 3+4 (MFMA, split-bf16, gload_lds staging) — unchanged from r4
// (verified passing at 964 us).
// ---------------------------------------------------------------------------
__global__ __launch_bounds__(256, 3) void stage34x_k(
    const u16* __restrict__ OUTAh, const u16* __restrict__ LATh,
    const u16* __restrict__ WriT, const u16* __restrict__ WupT,
    u16* __restrict__ yah)
{
    __shared__ __align__(16) u16 As[128 * 64];
    __shared__ __align__(16) u16 Bs[128 * 64];

    const int wg = xcd_swz(blockIdx.x, gridDim.x);
    const int n0 = (wg % 36) * 128, m0 = (wg / 36) * 128;
    const int k  = n0 / 384;
    const int tid  = threadIdx.x;
    const int lane = tid & 63, wave = tid >> 6;
    const int wm = (wave >> 1) * 64, wn = (wave & 1) * 64;
    const int lr = lane & 15, lg = lane >> 4;
    const int l8 = lane >> 3, l7 = lane & 7;

    f32x4 acc[4][4];
    #pragma unroll
    for (int i = 0; i < 4; i++)
        #pragma unroll
        for (int j = 0; j < 4; j++) acc[i][j] = (f32x4){0.f, 0.f, 0.f, 0.f};

    #pragma unroll
    for (int ph = 0; ph < 2; ph++) {
        const int Kd  = ph ? 192 : 128;
        const u16* Ab = ph ? LATh : OUTAh + k * 256;
        const int lda = ph ? 384 : 3072;
        const u16* Bb = ph ? WupT : WriT;
        const int ldb = ph ? 384 : 256;

        for (int k0 = 0; k0 < Kd; k0 += 32) {
            #pragma unroll
            for (int i = 0; i < 4; i++) {
                const int rl = i * 32 + wave * 8 + l8;
                const int q  = l7 ^ (rl & 7);
                const u16* gp = Ab + (long)(m0 + rl) * lda
                    + (q >= 4 ? Kd : 0) + k0 + ((q & 3) << 3);
                GLOAD16(gp, &As[i * 2048 + wave * 512 + lane * 8]);
            }
            #pragma unroll
            for (int i = 0; i < 4; i++) {
                const int rl = i * 32 + wave * 8 + l8;
                const int q  = l7 ^ (rl & 7);
                const u16* gp = Bb + (long)(n0 + rl) * ldb
                    + (q >= 4 ? Kd : 0) + k0 + ((q & 3) << 3);
                GLOAD16(gp, &Bs[i * 2048 + wave * 512 + lane * 8]);
            }
            __syncthreads();

            bf16x8 af[4], bh[4], bl[4];
            #pragma unroll
            for (int f = 0; f < 4; f++) {
                const int ra = wm + f * 16 + lr, rb = wn + f * 16 + lr;
                const int ca = ((lg << 4) ^ ((ra & 7) << 4)) >> 1;
                const int cbh = ((lg << 4) ^ ((rb & 7) << 4)) >> 1;
                const int cbl = (((64 + (lg << 4)) ^ ((rb & 7) << 4))) >> 1;
                af[f] = *(const bf16x8*)&As[ra * 64 + ca];
                bh[f] = *(const bf16x8*)&Bs[rb * 64 + cbh];
                bl[f] = *(const bf16x8*)&Bs[rb * 64 + cbl];
            }
            #pragma unroll
            for (int i = 0; i < 4; i++)
                #pragma unroll
                for (int j = 0; j < 4; j++)
                    acc[i][j] = __builtin_amdgcn_mfma_f32_16x16x32_bf16(af[i], bh[j], acc[i][j], 0, 0, 0);
            #pragma unroll
            for (int i = 0; i < 4; i++)
                #pragma unroll
                for (int j = 0; j < 4; j++)
                    acc[i][j] = __builtin_amdgcn_mfma_f32_16x16x32_bf16(af[i], bl[j], acc[i][j], 0, 0, 0);
            #pragma unroll
            for (int f = 0; f < 4; f++) {
                const int ra = wm + f * 16 + lr;
                const int ca = (((64 + (lg << 4)) ^ ((ra & 7) << 4))) >> 1;
                af[f] = *(const bf16x8*)&As[ra * 64 + ca];
            }
            #pragma unroll
            for (int i = 0; i < 4; i++)
                #pragma unroll
                for (int j = 0; j < 4; j++)
                    acc[i][j] = __builtin_amdgcn_mfma_f32_16x16x32_bf16(af[i], bh[j], acc[i][j], 0, 0, 0);
            __syncthreads();
        }
    }

    // epilogue: (yv,yg) interleaved in adjacent cols -> adjacent lanes
    #pragma unroll
    for (int i = 0; i < 4; i++) {
        #pragma unroll
        for (int j = 0; j < 4; j++) {
            const int gc  = n0 + wn + j * 16 + lr;
            const int yac = k * 192 + ((gc - k * 384) >> 1);
            #pragma unroll
            for (int r = 0; r < 4; r++) {
                const int gm = m0 + wm + i * 16 + lg * 4 + r;
                const float v = acc[i][j][r];
                const float p = __shfl_xor(v, 1);
                if (!(lane & 1)) {
                    const float g = p;
                    const float res = v * g * sigmoidf(g);
                    const u16 hh = f2bf(res);
                    const u16 ll = f2bf(res - bf2f(hh));
                    yah[(long)gm * 4608 + yac]        = hh;
                    yah[(long)gm * 4608 + 2304 + yac] = ll;
                }
            }
        }
    }
}

// ---------------------------------------------------------------------------
// Pack kernels (r4, except WallT padded to 1920 cols)
// ---------------------------------------------------------------------------
__global__ void packxh_k(const float* __restrict__ x, u16* __restrict__ xh,
                         long rows)
{
    const long n = rows * 768;
    for (long t = (long)blockIdx.x * blockDim.x + threadIdx.x; t < n;
         t += (long)gridDim.x * blockDim.x) {
        const long r = t / 768; const int c = (int)(t % 768);
        const float v = x[t];
        const u16 h = f2bf(v), l = f2bf(v - bf2f(h));
        xh[r * 1536 + c]       = h;
        xh[r * 1536 + 768 + c] = l;
    }
}

__global__ void packlat_k(const float* __restrict__ P, u16* __restrict__ LATh,
                          long rows)
{
    const long n = rows * 192;
    for (long t = (long)blockIdx.x * blockDim.x + threadIdx.x; t < n;
         t += (long)gridDim.x * blockDim.x) {
        const long r = t / 192; const int c = (int)(t % 192);
        const float v = P[r * PSTR_ + LOFF_ + c];
        const u16 h = f2bf(v), l = f2bf(v - bf2f(h));
        LATh[r * 384 + c]       = h;
        LATh[r * 384 + 192 + c] = l;
    }
}

__global__ void packwallT_k(const float* __restrict__ Wm, const float* __restrict__ Wq,
                            const float* __restrict__ Wg_, const float* __restrict__ Wd,
                            u16* __restrict__ WT)
{
    const int n = WPAD_ * 768;
    for (int t = blockIdx.x * blockDim.x + threadIdx.x; t < n;
         t += gridDim.x * blockDim.x) {
        const int c = t / 768, r = t % 768;
        float v = 0.f;
        if      (c < QOFF_) v = Wm[r * ZC_ + c];
        else if (c < GOFF_) v = Wq[r * 768 + (c - QOFF_)];
        else if (c < LOFF_) v = Wg_[r * 12 + (c - GOFF_)];
        else if (c < PSTR_) v = Wd[r * 192 + (c - LOFF_)];
        const u16 h = f2bf(v), l = f2bf(v - bf2f(h));
        WT[(long)c * 1536 + r]       = h;
        WT[(long)c * 1536 + 768 + r] = l;
    }
}

__global__ void packriT_k(const float* __restrict__ Wre, const float* __restrict__ Wim,
                          u16* __restrict__ WT)
{
    const int n = K_ * 384 * 128;
    for (int t = blockIdx.x * blockDim.x + threadIdx.x; t < n;
         t += gridDim.x * blockDim.x) {
        const int k = t / (384 * 128);
        const int rem = t % (384 * 128);
        const int cp = rem / 128, r = rem % 128;
        const int src = (cp >> 1) + 192 * (cp & 1);
        const float v = (r < 64) ? Wre[((long)k * 64 + r) * 384 + src]
                                 : Wim[((long)k * 64 + (r - 64)) * 384 + src];
        const u16 h = f2bf(v), l = f2bf(v - bf2f(h));
        const long base = ((long)k * 384 + cp) * 256;
        WT[base + r]       = h;
        WT[base + 128 + r] = l;
    }
}

__global__ void packupT_k(const float* __restrict__ Wup, const float* __restrict__ hw,
                          u16* __restrict__ WT)
{
    const int n = 4608 * 192;
    for (int t = blockIdx.x * blockDim.x + threadIdx.x; t < n;
         t += gridDim.x * blockDim.x) {
        const int c = t / 192, r = t % 192;
        const int k = c / 384, cp = c % 384;
        const int src = (cp >> 1) + 192 * (cp & 1);
        const float v = Wup[r * 4608 + k * 384 + src] * hw[k];
        const u16 h = f2bf(v), l = f2bf(v - bf2f(h));
        WT[(long)c * 384 + r]       = h;
        WT[(long)c * 384 + 192 + r] = l;
    }
}

__global__ void packoutT_k(const float* __restrict__ Wout, u16* __restrict__ WT)
{
    const int n = 768 * 2304;
    for (int t = blockIdx.x * blockDim.x + threadIdx.x; t < n;
         t += gridDim.x * blockDim.x) {
        const int c = t / 2304, r = t % 2304;
        const float v = Wout[(long)r * 768 + c];
        const u16 h = f2bf(v), l = f2bf(v - bf2f(h));
        WT[(long)c * 4608 + r]        = h;
        WT[(long)c * 4608 + 2304 + r] = l;
    }
}

// ---------------------------------------------------------------------------
// Fused scan (unchanged from r4): batch via blockIdx.z, emits OUTAh packed.
// ---------------------------------------------------------------------------
template<bool FINAL>
__global__ __launch_bounds__(64) void scan_k(
    const float* __restrict__ Pb, const float* __restrict__ convk,
    const float* __restrict__ theta, const float* __restrict__ decay,
    const float* __restrict__ ssc, const float* __restrict__ nsc,
    const float* __restrict__ bg, float* __restrict__ csumb,
    u16* __restrict__ OUTAhb)
{
    const int zb = blockIdx.z;
    const float* P  = Pb + (long)zb * L_ * PSTR_;
    float* csum     = csumb + (long)zb * K_ * CH2_ * 129;
    u16* OUTAh      = FINAL ? OUTAhb + (long)zb * L_ * 3072 : nullptr;

    const int ch = blockIdx.x, k = blockIdx.y, h = threadIdx.x;
    const int col = k * 64 + h, scol = 768 + k;
    const int l0 = ch * CL2_;

    const float ck0 = convk[col],  ck1 = convk[ZC_ + col];
    const float ck2 = convk[2 * ZC_ + col], ck3 = convk[3 * ZC_ + col];
    const float cs0 = convk[scol], cs1 = convk[ZC_ + scol];
    const float cs2 = convk[2 * ZC_ + scol], cs3 = convk[3 * ZC_ + scol];

    const float th    = softplusf(theta[k * 64 + h]) + 0.001f;
    const float slope = softplusf(decay[k]);
    const float sscal = ssc[k];
    const float ns    = FINAL ? nsc[k * 64 + h] : 0.f;
    const float bgk   = FINAL ? bg[k] : 0.f;
    const int   kq    = k >> 1;

    const long cb = ((long)k * CH2_ + ch) * 129;
    float dacc = 0.f, racc = 0.f, iacc = 0.f;
    if (FINAL) { dacc = csum[cb]; racc = csum[cb + 1 + h]; iacc = csum[cb + 65 + h]; }

    for (int p = 0; p < CL2_; p++) {
        const int l = l0 + p;
        float kv, sr;
        if (l >= 3) {
            const float* zb2 = P + (long)(l - 3) * PSTR_;
            kv = ck0 * zb2[col]  + ck1 * zb2[PSTR_ + col]
               + ck2 * zb2[2 * PSTR_ + col] + ck3 * zb2[3 * PSTR_ + col];
            sr = cs0 * zb2[scol] + cs1 * zb2[PSTR_ + scol]
               + cs2 * zb2[2 * PSTR_ + scol] + cs3 * zb2[3 * PSTR_ + scol];
        } else {
            kv = ck3 * P[(long)l * PSTR_ + col];
            sr = cs3 * P[(long)l * PSTR_ + scol];
            if (l >= 1) { kv += ck2 * P[(long)(l - 1) * PSTR_ + col];
                          sr += cs2 * P[(long)(l - 1) * PSTR_ + scol]; }
            if (l >= 2) { kv += ck1 * P[(long)(l - 2) * PSTR_ + col];
                          sr += cs1 * P[(long)(l - 2) * PSTR_ + scol]; }
        }
        const float lp = fminf(fmaxf(sscal * sr, -20.f), 20.f);
        const float pw = __expf(lp - slope * (float)(L_ - 1 - l));
        const float phi = tanhf(kv) * th;
        float sn, cn; __sincosf(phi, &sn, &cn);
        dacc += pw; racc += kv * pw * cn; iacc += kv * pw * sn;

        if (FINAL) {
            const float invd = 1.f / fmaxf(dacc, 1e-4f);
            const float sre = racc * invd, sim = iacc * invd;
            const float qr = P[(long)l * PSTR_ + QOFF_ + (kq * 64 + h) * 2];
            const float qi = P[(long)l * PSTR_ + QOFF_ + (kq * 64 + h) * 2 + 1];
            const float gate = sigmoidf(P[(long)l * PSTR_ + GOFF_ + k] + bgk);
            const float s2 = ns * gate;
            const float vre = (sre * qr + sim * qi) * s2;
            const float vim = (sim * qr - sre * qi) * s2;
            const u16 hre = f2bf(vre), him = f2bf(vim);
            const u16 lre = f2bf(vre - bf2f(hre));
            const u16 lim = f2bf(vim - bf2f(him));
            u16* orow = OUTAh + (long)l * 3072 + k * 256;
            orow[h]       = hre;
            orow[64 + h]  = him;
            orow[128 + h] = lre;
            orow[192 + h] = lim;
        }
    }
    if (!FINAL) {
        if (h == 0) csum[cb] = dacc;
        csum[cb + 1 + h]  = racc;
        csum[cb + 65 + h] = iacc;
    }
}

// exclusive prefix over the 128 chunks, per (batch=blockIdx.y, k, entry).
// Strip-mined: batch-load 32 independent, serial adds in regs, batch-store.
__global__ void scan2_k(float* __restrict__ csumb)
{
    float* csum = csumb + (long)blockIdx.y * K_ * CH2_ * 129;
    const int k = blockIdx.x;
    const int t = threadIdx.x;
    if (t >= 129) return;
    float run = 0.f;
    for (int g = 0; g < CH2_; g += 32) {
        float v[32];
        #pragma unroll
        for (int c = 0; c < 32; c++)
            v[c] = csum[((long)k * CH2_ + g + c) * 129 + t];
        #pragma unroll
        for (int c = 0; c < 32; c++) { const float x = v[c]; v[c] = run; run += x; }
        #pragma unroll
        for (int c = 0; c < 32; c++)
            csum[((long)k * CH2_ + g + c) * 129 + t] = v[c];
    }
}

// ---------------------------------------------------------------------------
extern "C" void kernel_launch(void* const* d_in, const int* in_sizes, int n_in,
                              void* d_out, int out_size, void* d_ws, size_t ws_size,
                              hipStream_t stream)
{
    float* out = (float*)d_out;   // f32 output (verified r8)
    const dim3 blk(256);

    // tripwire: input ordering/sizes
    const int expSz[16] = {12582912, 599040, 3120, 589824, 768, 12, 12,
                           294912, 294912, 768, 9216, 12, 147456, 884736,
                           12, 1769472};
    int bad = -1;
    if (n_in != 16) bad = 99;
    else { for (int i = 0; i < 16; i++) if (in_sizes[i] != expSz[i]) { bad = i; break; } }
    if (out_size != 12582912 && bad < 0) bad = 98;
    if (bad >= 0) {
        fillf_k<<<dim3(2048), blk, 0, stream>>>(out, out_size, 3000.f + bad);
        return;
    }

    const float* x     = (const float*)d_in[0];
    const float* W_mem = (const float*)d_in[1];
    const float* convk = (const float*)d_in[2];
    const float* W_q   = (const float*)d_in[3];
    const float* theta = (const float*)d_in[4];
    const float* decay = (const float*)d_in[5];
    const float* ssc   = (const float*)d_in[6];
    const float* W_re  = (const float*)d_in[7];
    const float* W_im  = (const float*)d_in[8];
    const float* nsc   = (const float*)d_in[9];
    const float* Wg    = (const float*)d_in[10];
    const float* bg    = (const float*)d_in[11];
    const float* W_dn  = (const float*)d_in[12];
    const float* W_up  = (const float*)d_in[13];
    const float* hw    = (const float*)d_in[14];
    const float* W_out = (const float*)d_in[15];

    // ---- workspace ladder: cfg0 full-batch everything; cfg1 per-batch
    //      activations + full yah; cfg2 everything per-batch.
    size_t o[12];
    auto plan = [&](bool fullP, bool fullY, size_t* oo) -> size_t {
        const long rp = fullP ? (long)B_ * L_ : L_;
        const long ry = fullY ? (long)B_ * L_ : L_;
        size_t off = 0;
        auto al = [&](size_t bytes) {
            size_t cur = off; off = (off + bytes + 255) & ~(size_t)255; return cur;
        };
        oo[0]  = al(4);                                   // md
        oo[1]  = al((size_t)B_ * K_ * CH2_ * 129 * 4);    // csum (all batches)
        oo[2]  = al((size_t)rp * 1536 * 2);               // xh (packed hi/lo)
        oo[3]  = al((size_t)rp * PSTR_ * 4);              // Pall (f32)
        oo[4]  = al((size_t)rp * 3072 * 2);               // OUTAh (packed)
        oo[5]  = al((size_t)rp * 384 * 2);                // LATh (packed)
        oo[6]  = al((size_t)ry * 4608 * 2);               // yah (packed)
        oo[7]  = al((size_t)WPAD_ * 1536 * 2);            // WallT (padded cols)
        oo[8]  = al((size_t)K_ * 384 * 256 * 2);          // WriT
        oo[9]  = al((size_t)4608 * 384 * 2);              // WupT
        oo[10] = al((size_t)768 * 4608 * 2);              // WoutT
        return off;
    };
    const int nCfg = 3;
    const bool cfgP[nCfg] = {true, false, false};
    const bool cfgY[nCfg] = {true, true,  false};
    int cfg = -1;
    for (int c = 0; c < nCfg; c++) {
        size_t t = plan(cfgP[c], cfgY[c], o);
        if (t + 4096 <= ws_size) { cfg = c; break; }
    }
    if (cfg < 0) {
        fillf_k<<<dim3(2048), blk, 0, stream>>>(out, (long)out_size, 1000.f);
        return;
    }
    const bool FULLP = cfgP[cfg], FULLY = cfgY[cfg];

    char* ws = (char*)d_ws;
    int*   md    = (int*)(ws + o[0]);
    float* csum  = (float*)(ws + o[1]);
    u16*   xh    = (u16*)(ws + o[2]);
    float* Pall  = (float*)(ws + o[3]);
    u16*   OUTAh = (u16*)(ws + o[4]);
    u16*   LATh  = (u16*)(ws + o[5]);
    u16*   yah   = (u16*)(ws + o[6]);
    u16*   WallT = (u16*)(ws + o[7]);
    u16*   WriT  = (u16*)(ws + o[8]);
    u16*   WupT  = (u16*)(ws + o[9]);
    u16*   WoutT = (u16*)(ws + o[10]);

    probe_k<<<dim3(1), dim3(64), 0, stream>>>((const unsigned*)ssc, md);
    packwallT_k<<<dim3(2048), blk, 0, stream>>>(W_mem, W_q, Wg, W_dn, WallT);
    packriT_k<<<dim3(1024), blk, 0, stream>>>(W_re, W_im, WriT);
    packupT_k<<<dim3(1024), blk, 0, stream>>>(W_up, hw, WupT);
    packoutT_k<<<dim3(2048), blk, 0, stream>>>(W_out, WoutT);

    const int nb    = FULLP ? 1 : B_;
    const long Mr   = FULLP ? (long)B_ * L_ : L_;
    const int nTm2  = (int)(Mr / 256);
    const int zGrid = FULLP ? B_ : 1;

    for (int b = 0; b < nb; b++) {
        const float* xb = x + (long)b * L_ * 768;

        // pack x -> hi/lo, then merged projection GEMM (8-phase): Pall = x @ Wall
        packxh_k<<<dim3(4096), blk, 0, stream>>>(xb, xh, Mr);
        gemm8_k<3><<<dim3(10 * nTm2), dim3(512), 0, stream>>>(
            xh, WallT, Pall, 1752, 768, 1536, 1536, 1752, 10);
        packlat_k<<<dim3(2048), blk, 0, stream>>>(Pall, LATh, Mr);

        // fused chunked scan, 3 passes -> OUTAh (packed)
        scan_k<false><<<dim3(CH2_, K_, zGrid), dim3(64), 0, stream>>>(
            Pall, convk, theta, decay, ssc, nsc, bg, csum, nullptr);
        scan2_k<<<dim3(K_, zGrid), dim3(192), 0, stream>>>(csum);
        scan_k<true><<<dim3(CH2_, K_, zGrid), dim3(64), 0, stream>>>(
            Pall, convk, theta, decay, ssc, nsc, bg, csum, OUTAh);

        // fused stage 3+4 -> ya (packed hi/lo bf16)
        u16* yd = (FULLY && !FULLP) ? yah + (long)b * L_ * 4608 : yah;
        stage34x_k<<<dim3(36 * (int)(Mr / 128)), blk, 0, stream>>>(
            OUTAh, LATh, WriT, WupT, yd);

        if (!FULLY) {
            gemm8_k<3><<<dim3(4 * nTm2), dim3(512), 0, stream>>>(
                yah, WoutT, out + (long)b * L_ * 768, 768, 2304, 4608, 4608, 768, 4);
        }
    }

    if (FULLY) {
        // one out-GEMM over all batches: (B*L) x 768, K=2304 (K'=6912), 256 blocks
        gemm8_k<3><<<dim3(4 * (int)((long)B_ * L_ / 256)), dim3(512), 0, stream>>>(
            yah, WoutT, out, 768, 2304, 4608, 4608, 768, 4);
    }

    guard_k<<<dim3(2048), blk, 0, stream>>>(md, out, (long)out_size);
}

// Round 7
// 647.977 us; speedup vs baseline: 1.7022x; 1.7022x over previous
//
#include <hip/hip_runtime.h>

typedef __attribute__((ext_vector_type(8))) _Float16 f16x8;
typedef __attribute__((ext_vector_type(4))) float f32x4;
typedef _Float16 f16;

#define B_    4
#define L_    4096
#define K_    12
#define ZC_   780        /* MEM + K */
#define CH2_  128        /* scan chunks */
#define CL2_  32         /* rows per chunk = L_/CH2_ */
#define PSTR_ 1752       /* packed projection row: 780 Z | 768 Q | 12 G | 192 LAT */
#define QOFF_ 780
#define GOFF_ 1548
#define LOFF_ 1560
#define WPAD_ 1792       /* WallT col padding: 14 tiles x 128 */

__device__ __forceinline__ float softplusf(float x){ return log1pf(__expf(x)); }
__device__ __forceinline__ float sigmoidf(float x){ return 1.f / (1.f + __expf(-x)); }

// async global->LDS, 16B per lane; LDS dest is linear (base + lane*16)
#define GLOAD16(gp, lp) __builtin_amdgcn_global_load_lds( \
    (const __attribute__((address_space(1))) unsigned int*)(gp), \
    (__attribute__((address_space(3))) unsigned int*)(lp), 16, 0, 0)

// bijective XCD swizzle (8 XCDs): contiguous wg chunk per XCD
__device__ __forceinline__ int xcd_swz(int bid, int nwg)
{
    const int q = nwg >> 3, r = nwg & 7;
    const int x = bid & 7, y = bid >> 3;
    return (x < r ? x * (q + 1) : r * (q + 1) + (x - r) * q) + y;
}

// dtype probe: score_scale == ones; f32 1.0 -> 0x3F800000
__global__ void probe_k(const unsigned* __restrict__ ss, int* __restrict__ md)
{
    if (threadIdx.x == 0 && blockIdx.x == 0) {
        unsigned w = ss[0];
        int m = 0;
        if      (w == 0x3F803F80u) m = 1;
        else if (w == 0x3C003C00u) m = 2;
        else if (w == 0x00000000u) m = 3;
        else if (w != 0x3F800000u) m = 4;
        md[0] = m;
    }
}

__global__ void fillf_k(float* __restrict__ p, long n, float v)
{
    for (long i = (long)blockIdx.x * blockDim.x + threadIdx.x; i < n;
         i += (long)gridDim.x * blockDim.x) p[i] = v;
}
__global__ void guard_k(const int* __restrict__ md, float* __restrict__ p, long n)
{
    const int m = *md;
    if (m == 0) return;
    for (long i = (long)blockIdx.x * blockDim.x + threadIdx.x; i < n;
         i += (long)gridDim.x * blockDim.x) p[i] = 4000.f + m;
}

// ---------------------------------------------------------------------------
// f16 single-product MFMA GEMM (r4-verified structure, BK=64).
// C[M,N] = A[M,Kd] @ B[Kd,N]; A [row][Kd] f16, B transposed [col][Kd] f16.
// Tile 128x128, 256 thr = 4 waves (2x2), 64x64/wave, 32 MFMA/wave/K-tile
// (mfma_f32_16x16x32_f16, kk=2 halves of the 64-wide K-tile).
// LDS [128][64] f16 per operand (16KB each); staging via global_load_lds
// with linear dest + inverse-XOR-swizzled source (chunk q = l7 ^ (row&7));
// fragment reads deswizzle c = (kk*4+lg) ^ (row&7) -> conflict-free
// (r4-verified SQ_LDS_BANK_CONFLICT = 0). 1D grid nTn*nTm, XCD-swizzled.
// M mult of 128, Kd mult of 64.
// ---------------------------------------------------------------------------
__global__ __launch_bounds__(256, 3) void gemmh_k(
    const f16* __restrict__ Ag, const f16* __restrict__ Bg,
    float* __restrict__ C, int N, int Kd, int lda, int ldb, int ldc, int nTn)
{
    __shared__ __align__(16) f16 As[128 * 64];
    __shared__ __align__(16) f16 Bs[128 * 64];

    const int wg = xcd_swz(blockIdx.x, gridDim.x);
    const int n0 = (wg % nTn) * 128, m0 = (wg / nTn) * 128;
    const int tid  = threadIdx.x;
    const int lane = tid & 63, wave = tid >> 6;
    const int wm = (wave >> 1) * 64, wn = (wave & 1) * 64;
    const int lr = lane & 15, lg = lane >> 4;
    const int l8 = lane >> 3, l7 = lane & 7;

    f32x4 acc[4][4];
    #pragma unroll
    for (int i = 0; i < 4; i++)
        #pragma unroll
        for (int j = 0; j < 4; j++) acc[i][j] = (f32x4){0.f, 0.f, 0.f, 0.f};

    for (int k0 = 0; k0 < Kd; k0 += 64) {
        #pragma unroll
        for (int i = 0; i < 4; i++) {           // A tile: 128 rows x 64 f16
            const int rl = i * 32 + wave * 8 + l8;
            const int q  = l7 ^ (rl & 7);
            GLOAD16(Ag + (long)(m0 + rl) * lda + k0 + q * 8,
                    &As[i * 2048 + wave * 512 + lane * 8]);
        }
        #pragma unroll
        for (int i = 0; i < 4; i++) {           // B tile
            const int rl = i * 32 + wave * 8 + l8;
            const int q  = l7 ^ (rl & 7);
            GLOAD16(Bg + (long)(n0 + rl) * ldb + k0 + q * 8,
                    &Bs[i * 2048 + wave * 512 + lane * 8]);
        }
        __syncthreads();

        f16x8 af[4][2], bf[4][2];
        #pragma unroll
        for (int f = 0; f < 4; f++) {
            #pragma unroll
            for (int kk = 0; kk < 2; kk++) {
                const int ra = wm + f * 16 + lr;
                const int ca = (kk * 4 + lg) ^ (ra & 7);
                af[f][kk] = *(const f16x8*)&As[ra * 64 + ca * 8];
                const int rb = wn + f * 16 + lr;
                const int cb = (kk * 4 + lg) ^ (rb & 7);
                bf[f][kk] = *(const f16x8*)&Bs[rb * 64 + cb * 8];
            }
        }
        #pragma unroll
        for (int i = 0; i < 4; i++)
            #pragma unroll
            for (int j = 0; j < 4; j++) {
                acc[i][j] = __builtin_amdgcn_mfma_f32_16x16x32_f16(af[i][0], bf[j][0], acc[i][j], 0, 0, 0);
                acc[i][j] = __builtin_amdgcn_mfma_f32_16x16x32_f16(af[i][1], bf[j][1], acc[i][j], 0, 0, 0);
            }
        __syncthreads();
    }

    // D layout: col = lane&15, row = (lane>>4)*4 + reg
    #pragma unroll
    for (int i = 0; i < 4; i++) {
        #pragma unroll
        for (int j = 0; j < 4; j++) {
            const int gn = n0 + wn + j * 16 + lr;
            if (gn < N) {
                #pragma unroll
                for (int r = 0; r < 4; r++) {
                    const int gm = m0 + wm + i * 16 + lg * 4 + r;
                    C[(long)gm * ldc + gn] = acc[i][j][r];
                }
            }
        }
    }
}

// ---------------------------------------------------------------------------
// Fused stage 3+4 (f16 single-product): per 128x128 tile of interleaved-Ysum,
// acc = OUTAh[:,k-block] @ WriT[k] (Kd=128) + LATh @ WupT (Kd=192);
// epilogue: ya = yv*silu(yg) via shfl_xor(1), written as single f16.
// 1D grid 36*nTm, XCD-swizzled. BK=64 tiles, same addressing as gemmh_k.
// ---------------------------------------------------------------------------
__global__ __launch_bounds__(256, 3) void stage34h_k(
    const f16* __restrict__ OUTAh, const f16* __restrict__ LATh,
    const f16* __restrict__ WriT, const f16* __restrict__ WupT,
    f16* __restrict__ yah)
{
    __shared__ __align__(16) f16 As[128 * 64];
    __shared__ __align__(16) f16 Bs[128 * 64];

    const int wg = xcd_swz(blockIdx.x, gridDim.x);
    const int n0 = (wg % 36) * 128, m0 = (wg / 36) * 128;
    const int k  = n0 / 384;
    const int tid  = threadIdx.x;
    const int lane = tid & 63, wave = tid >> 6;
    const int wm = (wave >> 1) * 64, wn = (wave & 1) * 64;
    const int lr = lane & 15, lg = lane >> 4;
    const int l8 = lane >> 3, l7 = lane & 7;

    f32x4 acc[4][4];
    #pragma unroll
    for (int i = 0; i < 4; i++)
        #pragma unroll
        for (int j = 0; j < 4; j++) acc[i][j] = (f32x4){0.f, 0.f, 0.f, 0.f};

    #pragma unroll
    for (int ph = 0; ph < 2; ph++) {
        const int Kd  = ph ? 192 : 128;
        const f16* Ab = ph ? LATh : OUTAh + k * 128;
        const int lda = ph ? 192 : 1536;
        const f16* Bb = ph ? WupT + (long)n0 * 192 : WriT + (long)(k * 384) * 128 + (long)(n0 - k * 384) * 128;
        const int ldb = ph ? 192 : 128;

        for (int k0 = 0; k0 < Kd; k0 += 64) {
            #pragma unroll
            for (int i = 0; i < 4; i++) {
                const int rl = i * 32 + wave * 8 + l8;
                const int q  = l7 ^ (rl & 7);
                GLOAD16(Ab + (long)(m0 + rl) * lda + k0 + q * 8,
                        &As[i * 2048 + wave * 512 + lane * 8]);
            }
            #pragma unroll
            for (int i = 0; i < 4; i++) {
                const int rl = i * 32 + wave * 8 + l8;
                const int q  = l7 ^ (rl & 7);
                GLOAD16(Bb + (long)rl * ldb + k0 + q * 8,
                        &Bs[i * 2048 + wave * 512 + lane * 8]);
            }
            __syncthreads();

            f16x8 af[4][2], bf[4][2];
            #pragma unroll
            for (int f = 0; f < 4; f++) {
                #pragma unroll
                for (int kk = 0; kk < 2; kk++) {
                    const int ra = wm + f * 16 + lr;
                    const int ca = (kk * 4 + lg) ^ (ra & 7);
                    af[f][kk] = *(const f16x8*)&As[ra * 64 + ca * 8];
                    const int rb = wn + f * 16 + lr;
                    const int cb = (kk * 4 + lg) ^ (rb & 7);
                    bf[f][kk] = *(const f16x8*)&Bs[rb * 64 + cb * 8];
                }
            }
            #pragma unroll
            for (int i = 0; i < 4; i++)
                #pragma unroll
                for (int j = 0; j < 4; j++) {
                    acc[i][j] = __builtin_amdgcn_mfma_f32_16x16x32_f16(af[i][0], bf[j][0], acc[i][j], 0, 0, 0);
                    acc[i][j] = __builtin_amdgcn_mfma_f32_16x16x32_f16(af[i][1], bf[j][1], acc[i][j], 0, 0, 0);
                }
            __syncthreads();
        }
    }

    // epilogue: (yv,yg) interleaved in adjacent cols -> adjacent lanes
    #pragma unroll
    for (int i = 0; i < 4; i++) {
        #pragma unroll
        for (int j = 0; j < 4; j++) {
            const int gc  = n0 + wn + j * 16 + lr;
            const int yac = k * 192 + ((gc - k * 384) >> 1);
            #pragma unroll
            for (int r = 0; r < 4; r++) {
                const int gm = m0 + wm + i * 16 + lg * 4 + r;
                const float v = acc[i][j][r];
                const float p = __shfl_xor(v, 1);
                if (!(lane & 1)) {
                    const float g = p;
                    yah[(long)gm * 2304 + yac] = (f16)(v * g * sigmoidf(g));
                }
            }
        }
    }
}

// ---------------------------------------------------------------------------
// Pack kernels (single f16 plane)
// ---------------------------------------------------------------------------
__global__ void packxh_k(const float* __restrict__ x, f16* __restrict__ xh, long n)
{
    for (long t = (long)blockIdx.x * blockDim.x + threadIdx.x; t < n;
         t += (long)gridDim.x * blockDim.x) xh[t] = (f16)x[t];
}

__global__ void packlat_k(const float* __restrict__ P, f16* __restrict__ LATh,
                          long rows)
{
    const long n = rows * 192;
    for (long t = (long)blockIdx.x * blockDim.x + threadIdx.x; t < n;
         t += (long)gridDim.x * blockDim.x) {
        const long r = t / 192; const int c = (int)(t % 192);
        LATh[t] = (f16)P[r * PSTR_ + LOFF_ + c];
    }
}

// WallT[1792][768] f16 transposed: [W_mem | W_q | Wg | W_dn], cols padded
__global__ void packwallT_k(const float* __restrict__ Wm, const float* __restrict__ Wq,
                            const float* __restrict__ Wg_, const float* __restrict__ Wd,
                            f16* __restrict__ WT)
{
    const int n = WPAD_ * 768;
    for (int t = blockIdx.x * blockDim.x + threadIdx.x; t < n;
         t += gridDim.x * blockDim.x) {
        const int c = t / 768, r = t % 768;
        float v = 0.f;
        if      (c < QOFF_) v = Wm[r * ZC_ + c];
        else if (c < GOFF_) v = Wq[r * 768 + (c - QOFF_)];
        else if (c < LOFF_) v = Wg_[r * 12 + (c - GOFF_)];
        else if (c < PSTR_) v = Wd[r * 192 + (c - LOFF_)];
        WT[t] = (f16)v;
    }
}

// WriT[(k*384+cp)][128] f16: interleaved col cp -> src (cp>>1)+192*(cp&1),
// rows r<64 from W_re, r>=64 from W_im
__global__ void packriT_k(const float* __restrict__ Wre, const float* __restrict__ Wim,
                          f16* __restrict__ WT)
{
    const int n = K_ * 384 * 128;
    for (int t = blockIdx.x * blockDim.x + threadIdx.x; t < n;
         t += gridDim.x * blockDim.x) {
        const int k = t / (384 * 128);
        const int rem = t % (384 * 128);
        const int cp = rem / 128, r = rem % 128;
        const int src = (cp >> 1) + 192 * (cp & 1);
        const float v = (r < 64) ? Wre[((long)k * 64 + r) * 384 + src]
                                 : Wim[((long)k * 64 + (r - 64)) * 384 + src];
        WT[t] = (f16)v;
    }
}

// WupT[c][192] f16: interleaved col of 4608, highway folded
__global__ void packupT_k(const float* __restrict__ Wup, const float* __restrict__ hw,
                          f16* __restrict__ WT)
{
    const int n = 4608 * 192;
    for (int t = blockIdx.x * blockDim.x + threadIdx.x; t < n;
         t += gridDim.x * blockDim.x) {
        const int c = t / 192, r = t % 192;
        const int k = c / 384, cp = c % 384;
        const int src = (cp >> 1) + 192 * (cp & 1);
        WT[t] = (f16)(Wup[r * 4608 + k * 384 + src] * hw[k]);
    }
}

// WoutT[n][2304] f16 (from W_out[2304][768])
__global__ void packoutT_k(const float* __restrict__ Wout, f16* __restrict__ WT)
{
    const int n = 768 * 2304;
    for (int t = blockIdx.x * blockDim.x + threadIdx.x; t < n;
         t += gridDim.x * blockDim.x) {
        const int c = t / 2304, r = t % 2304;
        WT[t] = (f16)Wout[(long)r * 768 + c];
    }
}

// ---------------------------------------------------------------------------
// Fused scan: batch via blockIdx.z; Z from Pall cols 0..779 (guarded halo).
// Pass1: per-(chunk,k) sums into csum[z][k][ch][129]. Pass3: prefix init,
// emit OUTAh f16 [l][1536]: per k-block 128: [h]=re, [64+h]=im.
// ---------------------------------------------------------------------------
template<bool FINAL>
__global__ __launch_bounds__(64) void scan_k(
    const float* __restrict__ Pb, const float* __restrict__ convk,
    const float* __restrict__ theta, const float* __restrict__ decay,
    const float* __restrict__ ssc, const float* __restrict__ nsc,
    const float* __restrict__ bg, float* __restrict__ csumb,
    f16* __restrict__ OUTAhb)
{
    const int zb = blockIdx.z;
    const float* P  = Pb + (long)zb * L_ * PSTR_;
    float* csum     = csumb + (long)zb * K_ * CH2_ * 129;
    f16* OUTAh      = FINAL ? OUTAhb + (long)zb * L_ * 1536 : nullptr;

    const int ch = blockIdx.x, k = blockIdx.y, h = threadIdx.x;
    const int col = k * 64 + h, scol = 768 + k;
    const int l0 = ch * CL2_;

    const float ck0 = convk[col],  ck1 = convk[ZC_ + col];
    const float ck2 = convk[2 * ZC_ + col], ck3 = convk[3 * ZC_ + col];
    const float cs0 = convk[scol], cs1 = convk[ZC_ + scol];
    const float cs2 = convk[2 * ZC_ + scol], cs3 = convk[3 * ZC_ + scol];

    const float th    = softplusf(theta[k * 64 + h]) + 0.001f;
    const float slope = softplusf(decay[k]);
    const float sscal = ssc[k];
    const float ns    = FINAL ? nsc[k * 64 + h] : 0.f;
    const float bgk   = FINAL ? bg[k] : 0.f;
    const int   kq    = k >> 1;

    const long cb = ((long)k * CH2_ + ch) * 129;
    float dacc = 0.f, racc = 0.f, iacc = 0.f;
    if (FINAL) { dacc = csum[cb]; racc = csum[cb + 1 + h]; iacc = csum[cb + 65 + h]; }

    for (int p = 0; p < CL2_; p++) {
        const int l = l0 + p;
        float kv, sr;
        if (l >= 3) {
            const float* zb2 = P + (long)(l - 3) * PSTR_;
            kv = ck0 * zb2[col]  + ck1 * zb2[PSTR_ + col]
               + ck2 * zb2[2 * PSTR_ + col] + ck3 * zb2[3 * PSTR_ + col];
            sr = cs0 * zb2[scol] + cs1 * zb2[PSTR_ + scol]
               + cs2 * zb2[2 * PSTR_ + scol] + cs3 * zb2[3 * PSTR_ + scol];
        } else {
            kv = ck3 * P[(long)l * PSTR_ + col];
            sr = cs3 * P[(long)l * PSTR_ + scol];
            if (l >= 1) { kv += ck2 * P[(long)(l - 1) * PSTR_ + col];
                          sr += cs2 * P[(long)(l - 1) * PSTR_ + scol]; }
            if (l >= 2) { kv += ck1 * P[(long)(l - 2) * PSTR_ + col];
                          sr += cs1 * P[(long)(l - 2) * PSTR_ + scol]; }
        }
        const float lp = fminf(fmaxf(sscal * sr, -20.f), 20.f);
        const float pw = __expf(lp - slope * (float)(L_ - 1 - l));
        const float phi = tanhf(kv) * th;
        float sn, cn; __sincosf(phi, &sn, &cn);
        dacc += pw; racc += kv * pw * cn; iacc += kv * pw * sn;

        if (FINAL) {
            const float invd = 1.f / fmaxf(dacc, 1e-4f);
            const float sre = racc * invd, sim = iacc * invd;
            const float qr = P[(long)l * PSTR_ + QOFF_ + (kq * 64 + h) * 2];
            const float qi = P[(long)l * PSTR_ + QOFF_ + (kq * 64 + h) * 2 + 1];
            const float gate = sigmoidf(P[(long)l * PSTR_ + GOFF_ + k] + bgk);
            const float s2 = ns * gate;
            f16* orow = OUTAh + (long)l * 1536 + k * 128;
            orow[h]      = (f16)((sre * qr + sim * qi) * s2);
            orow[64 + h] = (f16)((sim * qr - sre * qi) * s2);
        }
    }
    if (!FINAL) {
        if (h == 0) csum[cb] = dacc;
        csum[cb + 1 + h]  = racc;
        csum[cb + 65 + h] = iacc;
    }
}

// exclusive prefix over the 128 chunks, per (batch=blockIdx.y, k, entry).
// Strip-mined: batch-load 32 independent, serial adds in regs, batch-store.
__global__ void scan2_k(float* __restrict__ csumb)
{
    float* csum = csumb + (long)blockIdx.y * K_ * CH2_ * 129;
    const int k = blockIdx.x;
    const int t = threadIdx.x;
    if (t >= 129) return;
    float run = 0.f;
    for (int g = 0; g < CH2_; g += 32) {
        float v[32];
        #pragma unroll
        for (int c = 0; c < 32; c++)
            v[c] = csum[((long)k * CH2_ + g + c) * 129 + t];
        #pragma unroll
        for (int c = 0; c < 32; c++) { const float x = v[c]; v[c] = run; run += x; }
        #pragma unroll
        for (int c = 0; c < 32; c++)
            csum[((long)k * CH2_ + g + c) * 129 + t] = v[c];
    }
}

// ---------------------------------------------------------------------------
extern "C" void kernel_launch(void* const* d_in, const int* in_sizes, int n_in,
                              void* d_out, int out_size, void* d_ws, size_t ws_size,
                              hipStream_t stream)
{
    float* out = (float*)d_out;   // f32 output (verified r8)
    const dim3 blk(256);

    // tripwire: input ordering/sizes
    const int expSz[16] = {12582912, 599040, 3120, 589824, 768, 12, 12,
                           294912, 294912, 768, 9216, 12, 147456, 884736,
                           12, 1769472};
    int bad = -1;
    if (n_in != 16) bad = 99;
    else { for (int i = 0; i < 16; i++) if (in_sizes[i] != expSz[i]) { bad = i; break; } }
    if (out_size != 12582912 && bad < 0) bad = 98;
    if (bad >= 0) {
        fillf_k<<<dim3(2048), blk, 0, stream>>>(out, out_size, 3000.f + bad);
        return;
    }

    const float* x     = (const float*)d_in[0];
    const float* W_mem = (const float*)d_in[1];
    const float* convk = (const float*)d_in[2];
    const float* W_q   = (const float*)d_in[3];
    const float* theta = (const float*)d_in[4];
    const float* decay = (const float*)d_in[5];
    const float* ssc   = (const float*)d_in[6];
    const float* W_re  = (const float*)d_in[7];
    const float* W_im  = (const float*)d_in[8];
    const float* nsc   = (const float*)d_in[9];
    const float* Wg    = (const float*)d_in[10];
    const float* bg    = (const float*)d_in[11];
    const float* W_dn  = (const float*)d_in[12];
    const float* W_up  = (const float*)d_in[13];
    const float* hw    = (const float*)d_in[14];
    const float* W_out = (const float*)d_in[15];

    // ---- workspace ladder: cfg0 full-batch; cfg1 per-batch acts + full yah;
    //      cfg2 everything per-batch.
    size_t o[12];
    auto plan = [&](bool fullP, bool fullY, size_t* oo) -> size_t {
        const long rp = fullP ? (long)B_ * L_ : L_;
        const long ry = fullY ? (long)B_ * L_ : L_;
        size_t off = 0;
        auto al = [&](size_t bytes) {
            size_t cur = off; off = (off + bytes + 255) & ~(size_t)255; return cur;
        };
        oo[0]  = al(4);                                   // md
        oo[1]  = al((size_t)B_ * K_ * CH2_ * 129 * 4);    // csum (all batches)
        oo[2]  = al((size_t)rp * 768 * 2);                // xh (f16)
        oo[3]  = al((size_t)rp * PSTR_ * 4);              // Pall (f32)
        oo[4]  = al((size_t)rp * 1536 * 2);               // OUTAh (f16)
        oo[5]  = al((size_t)rp * 192 * 2);                // LATh (f16)
        oo[6]  = al((size_t)ry * 2304 * 2);               // yah (f16)
        oo[7]  = al((size_t)WPAD_ * 768 * 2);             // WallT
        oo[8]  = al((size_t)K_ * 384 * 128 * 2);          // WriT
        oo[9]  = al((size_t)4608 * 192 * 2);              // WupT
        oo[10] = al((size_t)768 * 2304 * 2);              // WoutT
        return off;
    };
    const int nCfg = 3;
    const bool cfgP[nCfg] = {true, false, false};
    const bool cfgY[nCfg] = {true, true,  false};
    int cfg = -1;
    for (int c = 0; c < nCfg; c++) {
        size_t t = plan(cfgP[c], cfgY[c], o);
        if (t + 4096 <= ws_size) { cfg = c; break; }
    }
    if (cfg < 0) {
        fillf_k<<<dim3(2048), blk, 0, stream>>>(out, (long)out_size, 1000.f);
        return;
    }
    const bool FULLP = cfgP[cfg], FULLY = cfgY[cfg];

    char* ws = (char*)d_ws;
    int*   md    = (int*)(ws + o[0]);
    float* csum  = (float*)(ws + o[1]);
    f16*   xh    = (f16*)(ws + o[2]);
    float* Pall  = (float*)(ws + o[3]);
    f16*   OUTAh = (f16*)(ws + o[4]);
    f16*   LATh  = (f16*)(ws + o[5]);
    f16*   yah   = (f16*)(ws + o[6]);
    f16*   WallT = (f16*)(ws + o[7]);
    f16*   WriT  = (f16*)(ws + o[8]);
    f16*   WupT  = (f16*)(ws + o[9]);
    f16*   WoutT = (f16*)(ws + o[10]);

    probe_k<<<dim3(1), dim3(64), 0, stream>>>((const unsigned*)ssc, md);
    packwallT_k<<<dim3(2048), blk, 0, stream>>>(W_mem, W_q, Wg, W_dn, WallT);
    packriT_k<<<dim3(1024), blk, 0, stream>>>(W_re, W_im, WriT);
    packupT_k<<<dim3(1024), blk, 0, stream>>>(W_up, hw, WupT);
    packoutT_k<<<dim3(2048), blk, 0, stream>>>(W_out, WoutT);

    const int nb    = FULLP ? 1 : B_;
    const long Mr   = FULLP ? (long)B_ * L_ : L_;
    const int nTm   = (int)(Mr / 128);
    const int zGrid = FULLP ? B_ : 1;

    for (int b = 0; b < nb; b++) {
        const float* xb = x + (long)b * L_ * 768;

        // pack x -> f16, then merged projection GEMM: Pall = x @ Wall
        packxh_k<<<dim3(4096), blk, 0, stream>>>(xb, xh, Mr * 768);
        gemmh_k<<<dim3(14 * nTm), blk, 0, stream>>>(
            xh, WallT, Pall, 1752, 768, 768, 768, 1752, 14);
        packlat_k<<<dim3(2048), blk, 0, stream>>>(Pall, LATh, Mr);

        // fused chunked scan, 3 passes -> OUTAh (f16)
        scan_k<false><<<dim3(CH2_, K_, zGrid), dim3(64), 0, stream>>>(
            Pall, convk, theta, decay, ssc, nsc, bg, csum, nullptr);
        scan2_k<<<dim3(K_, zGrid), dim3(192), 0, stream>>>(csum);
        scan_k<true><<<dim3(CH2_, K_, zGrid), dim3(64), 0, stream>>>(
            Pall, convk, theta, decay, ssc, nsc, bg, csum, OUTAh);

        // fused stage 3+4 -> ya (f16)
        f16* yd = (FULLY && !FULLP) ? yah + (long)b * L_ * 2304 : yah;
        stage34h_k<<<dim3(36 * nTm), blk, 0, stream>>>(
            OUTAh, LATh, WriT, WupT, yd);

        if (!FULLY) {
            gemmh_k<<<dim3(6 * nTm), blk, 0, stream>>>(
                yah, WoutT, out + (long)b * L_ * 768, 768, 2304, 2304, 2304, 768, 6);
        }
    }

    if (FULLY) {
        // one out-GEMM over all batches: (B*L) x 768, Kd=2304
        gemmh_k<<<dim3(6 * (int)((long)B_ * L_ / 128)), blk, 0, stream>>>(
            yah, WoutT, out, 768, 2304, 2304, 2304, 768, 6);
    }

    guard_k<<<dim3(2048), blk, 0, stream>>>(md, out, (long)out_size);
}